// Round 4
// baseline (915.070 us; speedup 1.0000x reference)
//
#include <hip/hip_runtime.h>

typedef __bf16 bf16;
typedef __bf16 bf16x4 __attribute__((ext_vector_type(4)));
typedef __bf16 bf16x8 __attribute__((ext_vector_type(8)));
typedef float f32x4 __attribute__((ext_vector_type(4)));

#define MFMA(a, b, c) __builtin_amdgcn_mfma_f32_16x16x32_bf16((a), (b), (c), 0, 0, 0)

constexpr size_t SEC = (size_t)2048 * 8 * 64 * 64;  // elems per q/k/v section

template <bool B> struct BC { static constexpr bool v = B; };

__device__ __forceinline__ void gload16(const void* g, void* l) {
  __builtin_amdgcn_global_load_lds((const __attribute__((address_space(1))) void*)g,
                                   (__attribute__((address_space(3))) void*)l, 16, 0, 0);
}

// ---------------- prep: out[c][r] = bf16(in[r][c]) ----------------
__global__ void transpose_cast(const float* __restrict__ in, bf16* __restrict__ out,
                               int R, int C) {
  int i = blockIdx.x * 256 + threadIdx.x;
  if (i >= R * C) return;
  int r = i / C, c = i - r * C;
  out[(size_t)c * R + r] = (bf16)in[i];
}

// ---------------- small GEMM for tbias: C = A(f32) @ Bt^T + bias ----------------
__global__ __launch_bounds__(256) void gemm_temb(
    const float* __restrict__ Ap, const bf16* __restrict__ Bt,
    const float* __restrict__ bias, float* __restrict__ C,
    int M, int N, int K) {
  __shared__ bf16 lA[128 * 32];
  __shared__ bf16 lB[128 * 32];
  const int t = threadIdx.x, l = t & 63;
  const int w = t >> 6, wr = w >> 1, wc = w & 1;
  const int li = l & 15, kl = (l >> 4) << 3;
  const long bm0 = (long)blockIdx.x * 128, bn0 = (long)blockIdx.y * 128;
  f32x4 acc[4][4] = {};
  for (int ks = 0; ks < (K >> 5); ++ks) {
    const int k0 = ks << 5;
    __syncthreads();
#pragma unroll
    for (int i = 0; i < 2; ++i) {
      int u = t + (i << 8);
      int row = u >> 2, kc = (u & 3) << 3;
      const float* ag = Ap + (bm0 + row) * K + k0 + kc;
      f32x4 v0 = *((const f32x4*)ag);
      f32x4 v1 = *((const f32x4*)(ag + 4));
      bf16x8 pk;
      pk[0] = (bf16)v0[0]; pk[1] = (bf16)v0[1]; pk[2] = (bf16)v0[2]; pk[3] = (bf16)v0[3];
      pk[4] = (bf16)v1[0]; pk[5] = (bf16)v1[1]; pk[6] = (bf16)v1[2]; pk[7] = (bf16)v1[3];
      *((bf16x8*)&lA[u << 3]) = pk;
      *((bf16x8*)&lB[u << 3]) = *((const bf16x8*)&Bt[(bn0 + row) * K + k0 + kc]);
    }
    __syncthreads();
    bf16x8 af[4], bfr[4];
#pragma unroll
    for (int mt = 0; mt < 4; ++mt)
      af[mt] = *((const bf16x8*)&lA[(wr * 64 + mt * 16 + li) * 32 + kl]);
#pragma unroll
    for (int nt = 0; nt < 4; ++nt)
      bfr[nt] = *((const bf16x8*)&lB[(wc * 64 + nt * 16 + li) * 32 + kl]);
#pragma unroll
    for (int mt = 0; mt < 4; ++mt)
#pragma unroll
      for (int nt = 0; nt < 4; ++nt)
        acc[mt][nt] = MFMA(af[mt], bfr[nt], acc[mt][nt]);
  }
#pragma unroll
  for (int mt = 0; mt < 4; ++mt)
#pragma unroll
    for (int nt = 0; nt < 4; ++nt) {
      long col = bn0 + wc * 64 + nt * 16 + li;
      float bv = bias[col];
#pragma unroll
      for (int r = 0; r < 4; ++r) {
        long row = bm0 + wr * 64 + mt * 16 + ((l >> 4) << 2) + r;
        C[row * N + col] = acc[mt][nt][r] + bv;
      }
    }
}

// ---------------- big GEMMs: 128x128 tile, BK=32, K=512, swizzled LDS --------
// MODE 0: proj.  A = O bf16 stored [b][h][n][d] (q-region of qkv buf), B = w2t,
//         bias = b_proj, out = fp32 [131072][512].
// MODE 1: qkv.   A = x fp32 (reg-staged + prefetch), B = w1t, bias = tb[b][col],
//         cols 0..1023 -> q/k tiles [b][h][n][d] (q pre-scaled);
//         cols 1024..1535 -> swapped MFMA, vT tiles [b][h][d][n].
template <int MODE>
__global__ __launch_bounds__(256) void mm128(
    const void* __restrict__ Ap, const bf16* __restrict__ Bt,
    const float* __restrict__ biasv, void* __restrict__ Cp) {
  __shared__ bf16 lA[128 * 32];
  __shared__ bf16 lB[128 * 32];
  const int t = threadIdx.x, l = t & 63;
  const int w = t >> 6, wr = w >> 1, wc = w & 1;
  const int li = l & 15, lg = l >> 4;
  const int bm0 = blockIdx.y * 128;
  const int bnG = blockIdx.x * 128;
  const bool isv = (MODE == 1) && (bnG >= 1024);
  const int arow = t >> 1, acol = (t & 1) << 4;  // fp32 A staging slot (MODE 1)

  f32x4 acc[4][4] = {};

  auto kloop = [&](auto swc) {
    constexpr bool SW = decltype(swc)::v;
    f32x4 pf[4];
    if (MODE == 1) {
      const float* xg = (const float*)Ap + (size_t)(bm0 + arow) * 512 + acol;
#pragma unroll
      for (int j = 0; j < 4; ++j) pf[j] = *((const f32x4*)(xg + 4 * j));
    }
    for (int ks = 0; ks < 16; ++ks) {
      const int k0 = ks << 5;
      __syncthreads();
      if (MODE == 1) {
        // A: cast prefetched fp32 -> bf16, swizzled ds_write
#pragma unroll
        for (int j = 0; j < 2; ++j) {
          bf16x8 pk;
#pragma unroll
          for (int e = 0; e < 4; ++e) {
            pk[e] = (bf16)pf[2 * j][e];
            pk[e + 4] = (bf16)pf[2 * j + 1][e];
          }
          int s = (acol >> 3) + j;
          int p = s ^ ((arow >> 1) & 3);
          *((bf16x8*)&lA[arow * 32 + p * 8]) = pk;
        }
      } else {
        // A via gload from O-in-qkv (layout [b][h][n][d])
#pragma unroll
        for (int i = 0; i < 2; ++i) {
          int u = t + (i << 8);
          int row = u >> 2, p = u & 3;
          int c0 = k0 + ((p ^ ((row >> 1) & 3)) << 3);
          int gr = bm0 + row;
          const bf16* src = (const bf16*)Ap +
                            (((size_t)(gr >> 6) * 8 + (c0 >> 6)) << 12) +
                            (gr & 63) * 64 + (c0 & 63);
          gload16(src, &lA[(w * 64 + (i << 8)) * 8]);
        }
      }
#pragma unroll
      for (int i = 0; i < 2; ++i) {
        int u = t + (i << 8);
        int row = u >> 2, p = u & 3;
        int c0 = k0 + ((p ^ ((row >> 1) & 3)) << 3);
        gload16(Bt + (size_t)(bnG + row) * 512 + c0, &lB[(w * 64 + (i << 8)) * 8]);
      }
      __syncthreads();
      if (MODE == 1 && ks < 15) {  // prefetch next A-tile; flies through compute
        const float* xg = (const float*)Ap + (size_t)(bm0 + arow) * 512 + k0 + 32 + acol;
#pragma unroll
        for (int j = 0; j < 4; ++j) pf[j] = *((const f32x4*)(xg + 4 * j));
      }
      bf16x8 af[4], bfr[4];
#pragma unroll
      for (int mt = 0; mt < 4; ++mt) {
        int row = wr * 64 + mt * 16 + li;
        af[mt] = *((const bf16x8*)&lA[row * 32 + ((lg ^ ((row >> 1) & 3)) << 3)]);
      }
#pragma unroll
      for (int nt = 0; nt < 4; ++nt) {
        int row = wc * 64 + nt * 16 + li;
        bfr[nt] = *((const bf16x8*)&lB[row * 32 + ((lg ^ ((row >> 1) & 3)) << 3)]);
      }
#pragma unroll
      for (int mt = 0; mt < 4; ++mt)
#pragma unroll
        for (int nt = 0; nt < 4; ++nt)
          acc[mt][nt] = SW ? MFMA(bfr[nt], af[mt], acc[mt][nt])
                           : MFMA(af[mt], bfr[nt], acc[mt][nt]);
    }
  };
  if (isv) kloop(BC<true>{}); else kloop(BC<false>{});

  if (MODE == 0) {
    float* C = (float*)Cp;
#pragma unroll
    for (int nt = 0; nt < 4; ++nt) {
      int col = bnG + wc * 64 + nt * 16 + li;
      float bv = biasv[col];
#pragma unroll
      for (int mt = 0; mt < 4; ++mt) {
        int row = bm0 + wr * 64 + mt * 16 + (lg << 2);
#pragma unroll
        for (int r = 0; r < 4; ++r)
          C[(size_t)(row + r) * 512 + col] = acc[mt][nt][r] + bv;
      }
    }
  } else if (!isv) {
    // q/k epilogue: rows are tokens, cols are qkv-cols 0..1023
    bf16* qkv = (bf16*)Cp;
    const int b = (bm0 >> 6) + wr;  // wave-uniform window index
#pragma unroll
    for (int nt = 0; nt < 4; ++nt) {
      int col = bnG + wc * 64 + nt * 16 + li;
      int sec = col >> 9, h = (col >> 6) & 7, d = col & 63;
      float bv = biasv[(size_t)b * 1536 + col];
      float sc = (sec == 0) ? 0.125f : 1.0f;
      bf16* dst = qkv + (size_t)sec * SEC + (((size_t)b * 8 + h) << 12) + d;
#pragma unroll
      for (int mt = 0; mt < 4; ++mt) {
        int n0 = mt * 16 + (lg << 2);
#pragma unroll
        for (int r = 0; r < 4; ++r)
          dst[(n0 + r) * 64] = (bf16)((acc[mt][nt][r] + bv) * sc);
      }
    }
  } else {
    // v epilogue (swapped): rows of acc are qkv-cols, cols of acc are tokens
    bf16* qkv = (bf16*)Cp;
    const int b = (bm0 >> 6) + wr;
#pragma unroll
    for (int nt = 0; nt < 4; ++nt) {
      int colb = bnG + wc * 64 + nt * 16 + (lg << 2);
#pragma unroll
      for (int r = 0; r < 4; ++r) {
        int col = colb + r;
        int h = (col >> 6) & 7, d = col & 63;
        float bv = biasv[(size_t)b * 1536 + col];
        bf16* dst = qkv + 2 * SEC + (((size_t)b * 8 + h) << 12) + d * 64;
#pragma unroll
        for (int mt = 0; mt < 4; ++mt) {
          int n = mt * 16 + li;
          dst[n] = (bf16)(acc[mt][nt][r] + bv);
        }
      }
    }
  }
}

// ---------------- attention: one window per block, 4 waves, dbuf heads -------
__global__ __launch_bounds__(256, 4) void attn_win(bf16* qkv,
                                                   const float* __restrict__ rpb) {
  __shared__ bf16 stg[2][3][4096];  // [buf][q|k|vT][64*64], XOR-swizzled rows
  const int b = blockIdx.x, t = threadIdx.x, l = t & 63, w = t >> 6;
  const int li = l & 15, lg = l >> 4;

  int rpidx[4][4];
#pragma unroll
  for (int ct = 0; ct < 4; ++ct)
#pragma unroll
    for (int r = 0; r < 4; ++r) {
      int n = 16 * w + (lg << 2) + r, m = 16 * ct + li;
      rpidx[ct][r] = (((n >> 3) - (m >> 3) + 7) * 15 + ((n & 7) - (m & 7) + 7)) * 8;
    }

  auto stage = [&](int h, int buf) {
#pragma unroll
    for (int tt = 0; tt < 3; ++tt) {
      const bf16* src = qkv + (size_t)tt * SEC + (((size_t)b * 8 + h) << 12);
#pragma unroll
      for (int i = 0; i < 2; ++i) {
        int u = t + (i << 8);
        int row = u >> 3, s = u & 7;
        gload16(src + row * 64 + ((s ^ (row & 7)) << 3),
                &stg[buf][tt][(w * 64 + (i << 8)) * 8]);
      }
    }
  };

  stage(0, 0);
  for (int h = 0; h < 8; ++h) {
    const int buf = h & 1;
    __syncthreads();           // drains stage(h) loads (vmcnt0) + syncs waves
    if (h < 7) stage(h + 1, buf ^ 1);  // in flight through compute
    bf16* Q = stg[buf][0];
    const bf16* K = stg[buf][1];
    const bf16* V = stg[buf][2];

    // S = (q*scale) @ k^T : wave owns rows [16w, 16w+16)
    f32x4 accS[4] = {};
#pragma unroll
    for (int kk = 0; kk < 2; ++kk) {
      int row = 16 * w + li;
      bf16x8 aq = *((const bf16x8*)&Q[row * 64 + (((kk * 4 + lg) ^ (row & 7)) << 3)]);
#pragma unroll
      for (int ct = 0; ct < 4; ++ct) {
        int kr = 16 * ct + li;
        bf16x8 bk = *((const bf16x8*)&K[kr * 64 + (((kk * 4 + lg) ^ (kr & 7)) << 3)]);
        accS[ct] = MFMA(aq, bk, accS[ct]);
      }
    }
    // softmax with rel-pos bias
    const float* rpbh = rpb + h;
    float sv[4][4], rsum[4];
#pragma unroll
    for (int ct = 0; ct < 4; ++ct)
#pragma unroll
      for (int r = 0; r < 4; ++r)
        sv[ct][r] = accS[ct][r] + rpbh[rpidx[ct][r]];
#pragma unroll
    for (int r = 0; r < 4; ++r) {
      float m = fmaxf(fmaxf(sv[0][r], sv[1][r]), fmaxf(sv[2][r], sv[3][r]));
      m = fmaxf(m, __shfl_xor(m, 1));
      m = fmaxf(m, __shfl_xor(m, 2));
      m = fmaxf(m, __shfl_xor(m, 4));
      m = fmaxf(m, __shfl_xor(m, 8));
      float s = 0.f;
#pragma unroll
      for (int ct = 0; ct < 4; ++ct) {
        float p = __expf(sv[ct][r] - m);
        sv[ct][r] = p;
        s += p;
      }
      s += __shfl_xor(s, 1);
      s += __shfl_xor(s, 2);
      s += __shfl_xor(s, 4);
      s += __shfl_xor(s, 8);
      rsum[r] = s;
    }
    // P -> Q tile (own strip rows only)
#pragma unroll
    for (int ct = 0; ct < 4; ++ct)
#pragma unroll
      for (int r = 0; r < 4; ++r) {
        int row = 16 * w + (lg << 2) + r;
        int col = 16 * ct + li;
        Q[row * 64 + (((col >> 3) ^ (row & 7)) << 3) + (col & 7)] = (bf16)sv[ct][r];
      }
    // O = P @ V
    f32x4 accO[4] = {};
#pragma unroll
    for (int kk = 0; kk < 2; ++kk) {
      int row = 16 * w + li;
      bf16x8 ap = *((const bf16x8*)&Q[row * 64 + (((kk * 4 + lg) ^ (row & 7)) << 3)]);
#pragma unroll
      for (int ct = 0; ct < 4; ++ct) {
        int vr = 16 * ct + li;
        bf16x8 bv = *((const bf16x8*)&V[vr * 64 + (((kk * 4 + lg) ^ (vr & 7)) << 3)]);
        accO[ct] = MFMA(ap, bv, accO[ct]);
      }
    }
    // O overwrites the q region: [b][h][n][d]
    bf16* ob = qkv + (((size_t)b * 8 + h) << 12);
    float rinv[4];
#pragma unroll
    for (int r = 0; r < 4; ++r) rinv[r] = 1.0f / rsum[r];
#pragma unroll
    for (int ct = 0; ct < 4; ++ct)
#pragma unroll
      for (int r = 0; r < 4; ++r)
        ob[(16 * w + (lg << 2) + r) * 64 + 16 * ct + li] = (bf16)(accO[ct][r] * rinv[r]);
  }
}

extern "C" void kernel_launch(void* const* d_in, const int* in_sizes, int n_in,
                              void* d_out, int out_size, void* d_ws, size_t ws_size,
                              hipStream_t stream) {
  (void)in_sizes; (void)n_in; (void)out_size; (void)ws_size;
  const float* x       = (const float*)d_in[0];
  const float* temb    = (const float*)d_in[1];
  const float* w_qkv   = (const float*)d_in[2];
  const float* b_qkv   = (const float*)d_in[3];
  const float* w_qkv_t = (const float*)d_in[4];
  const float* w_proj  = (const float*)d_in[5];
  const float* b_proj  = (const float*)d_in[6];
  const float* rpb     = (const float*)d_in[7];
  float* out = (float*)d_out;

  char* ws = (char*)d_ws;
  size_t off = 0;
  auto take = [&](size_t bytes) {
    void* p = ws + off;
    off += (bytes + 255) & ~(size_t)255;
    return p;
  };
  bf16* w1t  = (bf16*)take((size_t)1536 * 512 * 2);
  bf16* w3t  = (bf16*)take((size_t)1536 * 512 * 2);
  bf16* w2t  = (bf16*)take((size_t)512 * 512 * 2);
  float* tb  = (float*)take((size_t)2048 * 1536 * 4);
  bf16* qkv  = (bf16*)take(3 * SEC * 2);   // q/k [b][h][n][d], vT [b][h][d][n]

  transpose_cast<<<(512 * 1536 + 255) / 256, 256, 0, stream>>>(w_qkv, w1t, 512, 1536);
  transpose_cast<<<(512 * 1536 + 255) / 256, 256, 0, stream>>>(w_qkv_t, w3t, 512, 1536);
  transpose_cast<<<(512 * 512 + 255) / 256, 256, 0, stream>>>(w_proj, w2t, 512, 512);

  gemm_temb<<<dim3(2048 / 128, 1536 / 128), 256, 0, stream>>>(
      temb, w3t, b_qkv, tb, 2048, 1536, 512);

  mm128<1><<<dim3(12, 1024), 256, 0, stream>>>(x, w1t, tb, qkv);

  attn_win<<<2048, 256, 0, stream>>>(qkv, rpb);

  mm128<0><<<dim3(4, 1024), 256, 0, stream>>>(qkv, w2t, b_proj, out);
}

// Round 5
// 767.187 us; speedup vs baseline: 1.1928x; 1.1928x over previous
//
#include <hip/hip_runtime.h>

typedef __bf16 bf16;
typedef __bf16 bf16x4 __attribute__((ext_vector_type(4)));
typedef __bf16 bf16x8 __attribute__((ext_vector_type(8)));
typedef float f32x4 __attribute__((ext_vector_type(4)));

#define MFMA(a, b, c) __builtin_amdgcn_mfma_f32_16x16x32_bf16((a), (b), (c), 0, 0, 0)

constexpr size_t SEC = (size_t)2048 * 8 * 64 * 64;  // elems per q/k/v section

template <bool B> struct BC { static constexpr bool v = B; };

__device__ __forceinline__ void gload16(const void* g, void* l) {
  __builtin_amdgcn_global_load_lds((const __attribute__((address_space(1))) void*)g,
                                   (__attribute__((address_space(3))) void*)l, 16, 0, 0);
}

// ---------------- prep: out[c][r] = bf16(in[r][c]) ----------------
__global__ void transpose_cast(const float* __restrict__ in, bf16* __restrict__ out,
                               int R, int C) {
  int i = blockIdx.x * 256 + threadIdx.x;
  if (i >= R * C) return;
  int r = i / C, c = i - r * C;
  out[(size_t)c * R + r] = (bf16)in[i];
}

// ---------------- prep: x fp32 -> bf16, straight copy ----------------
__global__ __launch_bounds__(256) void cast_bf16(const float* __restrict__ in,
                                                 bf16* __restrict__ out) {
  size_t i = ((size_t)blockIdx.x * 256 + threadIdx.x) * 8;
  f32x4 v0 = *((const f32x4*)(in + i));
  f32x4 v1 = *((const f32x4*)(in + i + 4));
  bf16x8 pk;
  pk[0] = (bf16)v0[0]; pk[1] = (bf16)v0[1]; pk[2] = (bf16)v0[2]; pk[3] = (bf16)v0[3];
  pk[4] = (bf16)v1[0]; pk[5] = (bf16)v1[1]; pk[6] = (bf16)v1[2]; pk[7] = (bf16)v1[3];
  *((bf16x8*)(out + i)) = pk;
}

// ---------------- small GEMM for tbias: C = A(f32) @ Bt^T + bias ----------------
__global__ __launch_bounds__(256) void gemm_temb(
    const float* __restrict__ Ap, const bf16* __restrict__ Bt,
    const float* __restrict__ bias, float* __restrict__ C,
    int M, int N, int K) {
  __shared__ bf16 lA[128 * 32];
  __shared__ bf16 lB[128 * 32];
  const int t = threadIdx.x, l = t & 63;
  const int w = t >> 6, wr = w >> 1, wc = w & 1;
  const int li = l & 15, kl = (l >> 4) << 3;
  const long bm0 = (long)blockIdx.x * 128, bn0 = (long)blockIdx.y * 128;
  f32x4 acc[4][4] = {};
  for (int ks = 0; ks < (K >> 5); ++ks) {
    const int k0 = ks << 5;
    __syncthreads();
#pragma unroll
    for (int i = 0; i < 2; ++i) {
      int u = t + (i << 8);
      int row = u >> 2, kc = (u & 3) << 3;
      const float* ag = Ap + (bm0 + row) * K + k0 + kc;
      f32x4 v0 = *((const f32x4*)ag);
      f32x4 v1 = *((const f32x4*)(ag + 4));
      bf16x8 pk;
      pk[0] = (bf16)v0[0]; pk[1] = (bf16)v0[1]; pk[2] = (bf16)v0[2]; pk[3] = (bf16)v0[3];
      pk[4] = (bf16)v1[0]; pk[5] = (bf16)v1[1]; pk[6] = (bf16)v1[2]; pk[7] = (bf16)v1[3];
      *((bf16x8*)&lA[u << 3]) = pk;
      *((bf16x8*)&lB[u << 3]) = *((const bf16x8*)&Bt[(bn0 + row) * K + k0 + kc]);
    }
    __syncthreads();
    bf16x8 af[4], bfr[4];
#pragma unroll
    for (int mt = 0; mt < 4; ++mt)
      af[mt] = *((const bf16x8*)&lA[(wr * 64 + mt * 16 + li) * 32 + kl]);
#pragma unroll
    for (int nt = 0; nt < 4; ++nt)
      bfr[nt] = *((const bf16x8*)&lB[(wc * 64 + nt * 16 + li) * 32 + kl]);
#pragma unroll
    for (int mt = 0; mt < 4; ++mt)
#pragma unroll
      for (int nt = 0; nt < 4; ++nt)
        acc[mt][nt] = MFMA(af[mt], bfr[nt], acc[mt][nt]);
  }
#pragma unroll
  for (int mt = 0; mt < 4; ++mt)
#pragma unroll
    for (int nt = 0; nt < 4; ++nt) {
      long col = bn0 + wc * 64 + nt * 16 + li;
      float bv = bias[col];
#pragma unroll
      for (int r = 0; r < 4; ++r) {
        long row = bm0 + wr * 64 + mt * 16 + ((l >> 4) << 2) + r;
        C[row * N + col] = acc[mt][nt][r] + bv;
      }
    }
}

// ---------------- big GEMMs: 128x128 tile, BK=32, K=512 --------------------
// 2-phase pipeline (stage ks+1 || compute ks, one barrier/step), dbuf LDS,
// both operands via global_load_lds with pre-swizzled source columns
// (LDS linear, swizzled ds_read -> 0 bank conflicts, verified R4).
// 1D grid with XCD-chunked mapping: xcd = wg&7 owns 128 contiguous M-panels,
// N-blocks fastest -> x panel fetched into exactly one L2, once.
// MODE 0: proj (A = O bf16 in q-region, layout [b][h][n][d]); NB=4.
// MODE 1: qkv  (A = xb bf16 row-major); NB=12; epilogues scatter q/k/vT.
template <int MODE>
__global__ __launch_bounds__(256) void mm128(
    const void* __restrict__ Ap, const bf16* __restrict__ Bt,
    const float* __restrict__ biasv, void* __restrict__ Cp) {
  __shared__ bf16 lA[2][128 * 32];
  __shared__ bf16 lB[2][128 * 32];
  constexpr int NB = (MODE == 1) ? 12 : 4;
  const int t = threadIdx.x, l = t & 63;
  const int w = t >> 6, wr = w >> 1, wc = w & 1;
  const int li = l & 15, lg = l >> 4;

  const int wg = blockIdx.x;
  const int xcd = wg & 7, idx = wg >> 3;
  const int mb = xcd * 128 + idx / NB;   // 1024 M-panels, 128 per XCD
  const int nb = idx % NB;
  const int bm0 = mb * 128, bnG = nb * 128;
  const bool isv = (MODE == 1) && (bnG >= 1024);

  // staging geometry: unit u = t + i*256 -> row = u>>2, quad p = u&3
  const int srow = t >> 2, sp = t & 3;

  auto stage = [&](int ks, int buf) {
    const int k0 = ks << 5;
#pragma unroll
    for (int i = 0; i < 2; ++i) {
      int row = srow + (i << 6);
      int c0 = k0 + ((sp ^ ((row >> 1) & 3)) << 3);
      const bf16* asrc;
      if (MODE == 1) {
        asrc = (const bf16*)Ap + (size_t)(bm0 + row) * 512 + c0;
      } else {
        int gr = bm0 + row;
        asrc = (const bf16*)Ap + (((size_t)(gr >> 6) * 8 + (c0 >> 6)) << 12) +
               (gr & 63) * 64 + (c0 & 63);
      }
      gload16(asrc, &lA[buf][(w * 64 + (i << 8)) * 8]);
      gload16(Bt + (size_t)(bnG + row) * 512 + c0, &lB[buf][(w * 64 + (i << 8)) * 8]);
    }
  };

  f32x4 acc[4][4] = {};

  auto kloop = [&](auto swc) {
    constexpr bool SW = decltype(swc)::v;
    stage(0, 0);
    __syncthreads();
    int cb = 0;
    for (int ks = 0; ks < 16; ++ks) {
      if (ks < 15) stage(ks + 1, cb ^ 1);
      bf16x8 af[4], bfr[4];
#pragma unroll
      for (int mt = 0; mt < 4; ++mt) {
        int row = wr * 64 + mt * 16 + li;
        af[mt] = *((const bf16x8*)&lA[cb][row * 32 + ((lg ^ ((row >> 1) & 3)) << 3)]);
      }
#pragma unroll
      for (int nt = 0; nt < 4; ++nt) {
        int row = wc * 64 + nt * 16 + li;
        bfr[nt] = *((const bf16x8*)&lB[cb][row * 32 + ((lg ^ ((row >> 1) & 3)) << 3)]);
      }
#pragma unroll
      for (int mt = 0; mt < 4; ++mt)
#pragma unroll
        for (int nt = 0; nt < 4; ++nt)
          acc[mt][nt] = SW ? MFMA(bfr[nt], af[mt], acc[mt][nt])
                           : MFMA(af[mt], bfr[nt], acc[mt][nt]);
      __syncthreads();   // drains ks+1 loads (flew under compute) + buf swap
      cb ^= 1;
    }
  };
  if (isv) kloop(BC<true>{}); else kloop(BC<false>{});

  if (MODE == 0) {
    float* C = (float*)Cp;
#pragma unroll
    for (int nt = 0; nt < 4; ++nt) {
      int col = bnG + wc * 64 + nt * 16 + li;
      float bv = biasv[col];
#pragma unroll
      for (int mt = 0; mt < 4; ++mt) {
        int row = bm0 + wr * 64 + mt * 16 + (lg << 2);
#pragma unroll
        for (int r = 0; r < 4; ++r)
          C[(size_t)(row + r) * 512 + col] = acc[mt][nt][r] + bv;
      }
    }
  } else if (!isv) {
    // q/k epilogue: rows are tokens, cols are qkv-cols 0..1023
    bf16* qkv = (bf16*)Cp;
    const int b = (bm0 >> 6) + wr;
#pragma unroll
    for (int nt = 0; nt < 4; ++nt) {
      int col = bnG + wc * 64 + nt * 16 + li;
      int sec = col >> 9, h = (col >> 6) & 7, d = col & 63;
      float bv = biasv[(size_t)b * 1536 + col];
      float sc = (sec == 0) ? 0.125f : 1.0f;
      bf16* dst = qkv + (size_t)sec * SEC + (((size_t)b * 8 + h) << 12) + d;
#pragma unroll
      for (int mt = 0; mt < 4; ++mt) {
        int n0 = mt * 16 + (lg << 2);
#pragma unroll
        for (int r = 0; r < 4; ++r)
          dst[(n0 + r) * 64] = (bf16)((acc[mt][nt][r] + bv) * sc);
      }
    }
  } else {
    // v epilogue (swapped operands): acc rows = qkv-cols, acc cols = tokens
    bf16* qkv = (bf16*)Cp;
    const int b = (bm0 >> 6) + wr;
#pragma unroll
    for (int nt = 0; nt < 4; ++nt) {
      int colb = bnG + wc * 64 + nt * 16 + (lg << 2);
#pragma unroll
      for (int r = 0; r < 4; ++r) {
        int col = colb + r;
        int h = (col >> 6) & 7, d = col & 63;
        float bv = biasv[(size_t)b * 1536 + col];
        bf16* dst = qkv + 2 * SEC + (((size_t)b * 8 + h) << 12) + d * 64;
#pragma unroll
        for (int mt = 0; mt < 4; ++mt) {
          int n = mt * 16 + li;
          dst[n] = (bf16)(acc[mt][nt][r] + bv);
        }
      }
    }
  }
}

// ---------------- attention: one window per block, 4 waves, dbuf heads -------
__global__ __launch_bounds__(256, 4) void attn_win(bf16* qkv,
                                                   const float* __restrict__ rpb) {
  __shared__ bf16 stg[2][3][4096];  // [buf][q|k|vT][64*64], XOR-swizzled rows
  const int b = blockIdx.x, t = threadIdx.x, l = t & 63, w = t >> 6;
  const int li = l & 15, lg = l >> 4;

  int rpidx[4][4];
#pragma unroll
  for (int ct = 0; ct < 4; ++ct)
#pragma unroll
    for (int r = 0; r < 4; ++r) {
      int n = 16 * w + (lg << 2) + r, m = 16 * ct + li;
      rpidx[ct][r] = (((n >> 3) - (m >> 3) + 7) * 15 + ((n & 7) - (m & 7) + 7)) * 8;
    }

  auto stage = [&](int h, int buf) {
#pragma unroll
    for (int tt = 0; tt < 3; ++tt) {
      const bf16* src = qkv + (size_t)tt * SEC + (((size_t)b * 8 + h) << 12);
#pragma unroll
      for (int i = 0; i < 2; ++i) {
        int u = t + (i << 8);
        int row = u >> 3, s = u & 7;
        gload16(src + row * 64 + ((s ^ (row & 7)) << 3),
                &stg[buf][tt][(w * 64 + (i << 8)) * 8]);
      }
    }
  };

  stage(0, 0);
  for (int h = 0; h < 8; ++h) {
    const int buf = h & 1;
    __syncthreads();
    if (h < 7) stage(h + 1, buf ^ 1);
    bf16* Q = stg[buf][0];
    const bf16* K = stg[buf][1];
    const bf16* V = stg[buf][2];

    f32x4 accS[4] = {};
#pragma unroll
    for (int kk = 0; kk < 2; ++kk) {
      int row = 16 * w + li;
      bf16x8 aq = *((const bf16x8*)&Q[row * 64 + (((kk * 4 + lg) ^ (row & 7)) << 3)]);
#pragma unroll
      for (int ct = 0; ct < 4; ++ct) {
        int kr = 16 * ct + li;
        bf16x8 bk = *((const bf16x8*)&K[kr * 64 + (((kk * 4 + lg) ^ (kr & 7)) << 3)]);
        accS[ct] = MFMA(aq, bk, accS[ct]);
      }
    }
    const float* rpbh = rpb + h;
    float sv[4][4], rsum[4];
#pragma unroll
    for (int ct = 0; ct < 4; ++ct)
#pragma unroll
      for (int r = 0; r < 4; ++r)
        sv[ct][r] = accS[ct][r] + rpbh[rpidx[ct][r]];
#pragma unroll
    for (int r = 0; r < 4; ++r) {
      float m = fmaxf(fmaxf(sv[0][r], sv[1][r]), fmaxf(sv[2][r], sv[3][r]));
      m = fmaxf(m, __shfl_xor(m, 1));
      m = fmaxf(m, __shfl_xor(m, 2));
      m = fmaxf(m, __shfl_xor(m, 4));
      m = fmaxf(m, __shfl_xor(m, 8));
      float s = 0.f;
#pragma unroll
      for (int ct = 0; ct < 4; ++ct) {
        float p = __expf(sv[ct][r] - m);
        sv[ct][r] = p;
        s += p;
      }
      s += __shfl_xor(s, 1);
      s += __shfl_xor(s, 2);
      s += __shfl_xor(s, 4);
      s += __shfl_xor(s, 8);
      rsum[r] = s;
    }
#pragma unroll
    for (int ct = 0; ct < 4; ++ct)
#pragma unroll
      for (int r = 0; r < 4; ++r) {
        int row = 16 * w + (lg << 2) + r;
        int col = 16 * ct + li;
        Q[row * 64 + (((col >> 3) ^ (row & 7)) << 3) + (col & 7)] = (bf16)sv[ct][r];
      }
    f32x4 accO[4] = {};
#pragma unroll
    for (int kk = 0; kk < 2; ++kk) {
      int row = 16 * w + li;
      bf16x8 ap = *((const bf16x8*)&Q[row * 64 + (((kk * 4 + lg) ^ (row & 7)) << 3)]);
#pragma unroll
      for (int ct = 0; ct < 4; ++ct) {
        int vr = 16 * ct + li;
        bf16x8 bv = *((const bf16x8*)&V[vr * 64 + (((kk * 4 + lg) ^ (vr & 7)) << 3)]);
        accO[ct] = MFMA(ap, bv, accO[ct]);
      }
    }
    bf16* ob = qkv + (((size_t)b * 8 + h) << 12);
    float rinv[4];
#pragma unroll
    for (int r = 0; r < 4; ++r) rinv[r] = 1.0f / rsum[r];
#pragma unroll
    for (int ct = 0; ct < 4; ++ct)
#pragma unroll
      for (int r = 0; r < 4; ++r)
        ob[(16 * w + (lg << 2) + r) * 64 + 16 * ct + li] = (bf16)(accO[ct][r] * rinv[r]);
  }
}

extern "C" void kernel_launch(void* const* d_in, const int* in_sizes, int n_in,
                              void* d_out, int out_size, void* d_ws, size_t ws_size,
                              hipStream_t stream) {
  (void)in_sizes; (void)n_in; (void)out_size; (void)ws_size;
  const float* x       = (const float*)d_in[0];
  const float* temb    = (const float*)d_in[1];
  const float* w_qkv   = (const float*)d_in[2];
  const float* b_qkv   = (const float*)d_in[3];
  const float* w_qkv_t = (const float*)d_in[4];
  const float* w_proj  = (const float*)d_in[5];
  const float* b_proj  = (const float*)d_in[6];
  const float* rpb     = (const float*)d_in[7];
  float* out = (float*)d_out;

  char* ws = (char*)d_ws;
  size_t off = 0;
  auto take = [&](size_t bytes) {
    void* p = ws + off;
    off += (bytes + 255) & ~(size_t)255;
    return p;
  };
  bf16* w1t  = (bf16*)take((size_t)1536 * 512 * 2);
  bf16* w3t  = (bf16*)take((size_t)1536 * 512 * 2);
  bf16* w2t  = (bf16*)take((size_t)512 * 512 * 2);
  float* tb  = (float*)take((size_t)2048 * 1536 * 4);
  bf16* qkv  = (bf16*)take(3 * SEC * 2);          // q/k [b][h][n][d], vT [b][h][d][n]
  bf16* xb   = (bf16*)take((size_t)131072 * 512 * 2);  // x cast to bf16

  transpose_cast<<<(512 * 1536 + 255) / 256, 256, 0, stream>>>(w_qkv, w1t, 512, 1536);
  transpose_cast<<<(512 * 1536 + 255) / 256, 256, 0, stream>>>(w_qkv_t, w3t, 512, 1536);
  transpose_cast<<<(512 * 512 + 255) / 256, 256, 0, stream>>>(w_proj, w2t, 512, 512);

  cast_bf16<<<(131072 * 512 / 8) / 256, 256, 0, stream>>>(x, xb);

  gemm_temb<<<dim3(2048 / 128, 1536 / 128), 256, 0, stream>>>(
      temb, w3t, b_qkv, tb, 2048, 1536, 512);

  mm128<1><<<12 * 1024, 256, 0, stream>>>(xb, w1t, tb, qkv);

  attn_win<<<2048, 256, 0, stream>>>(qkv, rpb);

  mm128<0><<<4 * 1024, 256, 0, stream>>>(qkv, w2t, b_proj, out);
}

// Round 6
// 755.585 us; speedup vs baseline: 1.2111x; 1.0154x over previous
//
#include <hip/hip_runtime.h>

typedef __bf16 bf16;
typedef __bf16 bf16x4 __attribute__((ext_vector_type(4)));
typedef __bf16 bf16x8 __attribute__((ext_vector_type(8)));
typedef float f32x4 __attribute__((ext_vector_type(4)));

#define MFMA(a, b, c) __builtin_amdgcn_mfma_f32_16x16x32_bf16((a), (b), (c), 0, 0, 0)

constexpr size_t SEC = (size_t)2048 * 8 * 64 * 64;  // elems per q/k/v section

template <bool B> struct BC { static constexpr bool v = B; };

__device__ __forceinline__ void gload16(const void* g, void* l) {
  __builtin_amdgcn_global_load_lds((const __attribute__((address_space(1))) void*)g,
                                   (__attribute__((address_space(3))) void*)l, 16, 0, 0);
}

// ---------------- prep: out[c][r] = bf16(in[r][c]) ----------------
__global__ void transpose_cast(const float* __restrict__ in, bf16* __restrict__ out,
                               int R, int C) {
  int i = blockIdx.x * 256 + threadIdx.x;
  if (i >= R * C) return;
  int r = i / C, c = i - r * C;
  out[(size_t)c * R + r] = (bf16)in[i];
}

// ---------------- prep: x fp32 -> bf16, straight copy ----------------
__global__ __launch_bounds__(256) void cast_bf16(const float* __restrict__ in,
                                                 bf16* __restrict__ out) {
  size_t i = ((size_t)blockIdx.x * 256 + threadIdx.x) * 8;
  f32x4 v0 = *((const f32x4*)(in + i));
  f32x4 v1 = *((const f32x4*)(in + i + 4));
  bf16x8 pk;
  pk[0] = (bf16)v0[0]; pk[1] = (bf16)v0[1]; pk[2] = (bf16)v0[2]; pk[3] = (bf16)v0[3];
  pk[4] = (bf16)v1[0]; pk[5] = (bf16)v1[1]; pk[6] = (bf16)v1[2]; pk[7] = (bf16)v1[3];
  *((bf16x8*)(out + i)) = pk;
}

// ---------------- small GEMM for tbias: C = A(f32) @ Bt^T + bias ----------------
__global__ __launch_bounds__(256) void gemm_temb(
    const float* __restrict__ Ap, const bf16* __restrict__ Bt,
    const float* __restrict__ bias, float* __restrict__ C,
    int M, int N, int K) {
  __shared__ bf16 lA[128 * 32];
  __shared__ bf16 lB[128 * 32];
  const int t = threadIdx.x, l = t & 63;
  const int w = t >> 6, wr = w >> 1, wc = w & 1;
  const int li = l & 15, kl = (l >> 4) << 3;
  const long bm0 = (long)blockIdx.x * 128, bn0 = (long)blockIdx.y * 128;
  f32x4 acc[4][4] = {};
  for (int ks = 0; ks < (K >> 5); ++ks) {
    const int k0 = ks << 5;
    __syncthreads();
#pragma unroll
    for (int i = 0; i < 2; ++i) {
      int u = t + (i << 8);
      int row = u >> 2, kc = (u & 3) << 3;
      const float* ag = Ap + (bm0 + row) * K + k0 + kc;
      f32x4 v0 = *((const f32x4*)ag);
      f32x4 v1 = *((const f32x4*)(ag + 4));
      bf16x8 pk;
      pk[0] = (bf16)v0[0]; pk[1] = (bf16)v0[1]; pk[2] = (bf16)v0[2]; pk[3] = (bf16)v0[3];
      pk[4] = (bf16)v1[0]; pk[5] = (bf16)v1[1]; pk[6] = (bf16)v1[2]; pk[7] = (bf16)v1[3];
      *((bf16x8*)&lA[u << 3]) = pk;
      *((bf16x8*)&lB[u << 3]) = *((const bf16x8*)&Bt[(bn0 + row) * K + k0 + kc]);
    }
    __syncthreads();
    bf16x8 af[4], bfr[4];
#pragma unroll
    for (int mt = 0; mt < 4; ++mt)
      af[mt] = *((const bf16x8*)&lA[(wr * 64 + mt * 16 + li) * 32 + kl]);
#pragma unroll
    for (int nt = 0; nt < 4; ++nt)
      bfr[nt] = *((const bf16x8*)&lB[(wc * 64 + nt * 16 + li) * 32 + kl]);
#pragma unroll
    for (int mt = 0; mt < 4; ++mt)
#pragma unroll
      for (int nt = 0; nt < 4; ++nt)
        acc[mt][nt] = MFMA(af[mt], bfr[nt], acc[mt][nt]);
  }
#pragma unroll
  for (int mt = 0; mt < 4; ++mt)
#pragma unroll
    for (int nt = 0; nt < 4; ++nt) {
      long col = bn0 + wc * 64 + nt * 16 + li;
      float bv = bias[col];
#pragma unroll
      for (int r = 0; r < 4; ++r) {
        long row = bm0 + wr * 64 + mt * 16 + ((l >> 4) << 2) + r;
        C[row * N + col] = acc[mt][nt][r] + bv;
      }
    }
}

// ---------------- big GEMMs: 128x128 tile, BK=32, K=512 --------------------
// Depth-3 counted-vmcnt pipeline (T4): 5 LDS buffers (80 KB), raw s_barrier,
// s_waitcnt vmcnt(8) in steady state (2 tiles always in flight, never
// drained to 0 in the main loop). Both operands via global_load_lds with
// pre-swizzled source columns (LDS linear, swizzled ds_read, 0 conflicts).
// 1D grid, XCD-chunked: xcd = wg&7 owns 128 contiguous M-panels, N fastest.
// MODE 0: proj (A = O bf16 in q-region, layout [b][h][n][d]); NB=4.
// MODE 1: qkv  (A = xb bf16 row-major); NB=12; epilogues scatter q/k/vT.
template <int MODE>
__global__ __launch_bounds__(256) void mm128(
    const void* __restrict__ Ap, const bf16* __restrict__ Bt,
    const float* __restrict__ biasv, void* __restrict__ Cp) {
  __shared__ bf16 lA[5][128 * 32];
  __shared__ bf16 lB[5][128 * 32];
  constexpr int NB = (MODE == 1) ? 12 : 4;
  const int t = threadIdx.x, l = t & 63;
  const int w = t >> 6, wr = w >> 1, wc = w & 1;
  const int li = l & 15, lg = l >> 4;

  const int wg = blockIdx.x;
  const int xcd = wg & 7, idx = wg >> 3;
  const int mb = xcd * 128 + idx / NB;   // 1024 M-panels, 128 per XCD
  const int nb = idx % NB;
  const int bm0 = mb * 128, bnG = nb * 128;
  const bool isv = (MODE == 1) && (bnG >= 1024);

  const int srow = t >> 2, sp = t & 3;

  auto stage = [&](int ks, int buf) {
    const int k0 = ks << 5;
#pragma unroll
    for (int i = 0; i < 2; ++i) {
      int row = srow + (i << 6);
      int c0 = k0 + ((sp ^ ((row >> 1) & 3)) << 3);
      const bf16* asrc;
      if (MODE == 1) {
        asrc = (const bf16*)Ap + (size_t)(bm0 + row) * 512 + c0;
      } else {
        int gr = bm0 + row;
        asrc = (const bf16*)Ap + (((size_t)(gr >> 6) * 8 + (c0 >> 6)) << 12) +
               (gr & 63) * 64 + (c0 & 63);
      }
      gload16(asrc, &lA[buf][(w * 64 + (i << 8)) * 8]);
      gload16(Bt + (size_t)(bnG + row) * 512 + c0, &lB[buf][(w * 64 + (i << 8)) * 8]);
    }
  };

  f32x4 acc[4][4] = {};

  auto kloop = [&](auto swc) {
    constexpr bool SW = decltype(swc)::v;
    stage(0, 0);
    stage(1, 1);
    stage(2, 2);              // 12 loads/thread in flight
    int cb = 0, sb = 3;
    for (int ks = 0; ks < 16; ++ks) {
      // wait ONLY tile ks's 4 loads; keep 2 future tiles in flight
      if (ks < 14)       asm volatile("s_waitcnt vmcnt(8)" ::: "memory");
      else if (ks == 14) asm volatile("s_waitcnt vmcnt(4)" ::: "memory");
      else               asm volatile("s_waitcnt vmcnt(0)" ::: "memory");
      __builtin_amdgcn_s_barrier();  // all waves' tile-ks loads landed;
                                     // all waves done reading tile ks-1
      if (ks < 13) {                 // stage tile ks+3 into buf last read
        stage(ks + 3, sb);           // at iter ks-2 (2-barrier margin)
        sb = (sb == 4) ? 0 : sb + 1;
      }
      bf16x8 af[4], bfr[4];
#pragma unroll
      for (int mt = 0; mt < 4; ++mt) {
        int row = wr * 64 + mt * 16 + li;
        af[mt] = *((const bf16x8*)&lA[cb][row * 32 + ((lg ^ ((row >> 1) & 3)) << 3)]);
      }
#pragma unroll
      for (int nt = 0; nt < 4; ++nt) {
        int row = wc * 64 + nt * 16 + li;
        bfr[nt] = *((const bf16x8*)&lB[cb][row * 32 + ((lg ^ ((row >> 1) & 3)) << 3)]);
      }
#pragma unroll
      for (int mt = 0; mt < 4; ++mt)
#pragma unroll
        for (int nt = 0; nt < 4; ++nt)
          acc[mt][nt] = SW ? MFMA(bfr[nt], af[mt], acc[mt][nt])
                           : MFMA(af[mt], bfr[nt], acc[mt][nt]);
      cb = (cb == 4) ? 0 : cb + 1;
    }
  };
  if (isv) kloop(BC<true>{}); else kloop(BC<false>{});

  if (MODE == 0) {
    float* C = (float*)Cp;
#pragma unroll
    for (int nt = 0; nt < 4; ++nt) {
      int col = bnG + wc * 64 + nt * 16 + li;
      float bv = biasv[col];
#pragma unroll
      for (int mt = 0; mt < 4; ++mt) {
        int row = bm0 + wr * 64 + mt * 16 + (lg << 2);
#pragma unroll
        for (int r = 0; r < 4; ++r)
          C[(size_t)(row + r) * 512 + col] = acc[mt][nt][r] + bv;
      }
    }
  } else if (!isv) {
    // q/k epilogue: rows are tokens, cols are qkv-cols 0..1023
    bf16* qkv = (bf16*)Cp;
    const int b = (bm0 >> 6) + wr;
#pragma unroll
    for (int nt = 0; nt < 4; ++nt) {
      int col = bnG + wc * 64 + nt * 16 + li;
      int sec = col >> 9, h = (col >> 6) & 7, d = col & 63;
      float bv = biasv[(size_t)b * 1536 + col];
      float sc = (sec == 0) ? 0.125f : 1.0f;
      bf16* dst = qkv + (size_t)sec * SEC + (((size_t)b * 8 + h) << 12) + d;
#pragma unroll
      for (int mt = 0; mt < 4; ++mt) {
        int n0 = mt * 16 + (lg << 2);
#pragma unroll
        for (int r = 0; r < 4; ++r)
          dst[(n0 + r) * 64] = (bf16)((acc[mt][nt][r] + bv) * sc);
      }
    }
  } else {
    // v epilogue (swapped operands): acc rows = qkv-cols, acc cols = tokens
    bf16* qkv = (bf16*)Cp;
    const int b = (bm0 >> 6) + wr;
#pragma unroll
    for (int nt = 0; nt < 4; ++nt) {
      int colb = bnG + wc * 64 + nt * 16 + (lg << 2);
#pragma unroll
      for (int r = 0; r < 4; ++r) {
        int col = colb + r;
        int h = (col >> 6) & 7, d = col & 63;
        float bv = biasv[(size_t)b * 1536 + col];
        bf16* dst = qkv + 2 * SEC + (((size_t)b * 8 + h) << 12) + d * 64;
#pragma unroll
        for (int mt = 0; mt < 4; ++mt) {
          int n = mt * 16 + li;
          dst[n] = (bf16)(acc[mt][nt][r] + bv);
        }
      }
    }
  }
}

// ---------------- attention: one window per block, 4 waves, dbuf heads -------
__global__ __launch_bounds__(256, 4) void attn_win(bf16* qkv,
                                                   const float* __restrict__ rpb) {
  __shared__ bf16 stg[2][3][4096];  // [buf][q|k|vT][64*64], XOR-swizzled rows
  const int b = blockIdx.x, t = threadIdx.x, l = t & 63, w = t >> 6;
  const int li = l & 15, lg = l >> 4;

  int rpidx[4][4];
#pragma unroll
  for (int ct = 0; ct < 4; ++ct)
#pragma unroll
    for (int r = 0; r < 4; ++r) {
      int n = 16 * w + (lg << 2) + r, m = 16 * ct + li;
      rpidx[ct][r] = (((n >> 3) - (m >> 3) + 7) * 15 + ((n & 7) - (m & 7) + 7)) * 8;
    }

  auto stage = [&](int h, int buf) {
#pragma unroll
    for (int tt = 0; tt < 3; ++tt) {
      const bf16* src = qkv + (size_t)tt * SEC + (((size_t)b * 8 + h) << 12);
#pragma unroll
      for (int i = 0; i < 2; ++i) {
        int u = t + (i << 8);
        int row = u >> 3, s = u & 7;
        gload16(src + row * 64 + ((s ^ (row & 7)) << 3),
                &stg[buf][tt][(w * 64 + (i << 8)) * 8]);
      }
    }
  };

  stage(0, 0);
  for (int h = 0; h < 8; ++h) {
    const int buf = h & 1;
    __syncthreads();
    if (h < 7) stage(h + 1, buf ^ 1);
    bf16* Q = stg[buf][0];
    const bf16* K = stg[buf][1];
    const bf16* V = stg[buf][2];

    f32x4 accS[4] = {};
#pragma unroll
    for (int kk = 0; kk < 2; ++kk) {
      int row = 16 * w + li;
      bf16x8 aq = *((const bf16x8*)&Q[row * 64 + (((kk * 4 + lg) ^ (row & 7)) << 3)]);
#pragma unroll
      for (int ct = 0; ct < 4; ++ct) {
        int kr = 16 * ct + li;
        bf16x8 bk = *((const bf16x8*)&K[kr * 64 + (((kk * 4 + lg) ^ (kr & 7)) << 3)]);
        accS[ct] = MFMA(aq, bk, accS[ct]);
      }
    }
    const float* rpbh = rpb + h;
    float sv[4][4], rsum[4];
#pragma unroll
    for (int ct = 0; ct < 4; ++ct)
#pragma unroll
      for (int r = 0; r < 4; ++r)
        sv[ct][r] = accS[ct][r] + rpbh[rpidx[ct][r]];
#pragma unroll
    for (int r = 0; r < 4; ++r) {
      float m = fmaxf(fmaxf(sv[0][r], sv[1][r]), fmaxf(sv[2][r], sv[3][r]));
      m = fmaxf(m, __shfl_xor(m, 1));
      m = fmaxf(m, __shfl_xor(m, 2));
      m = fmaxf(m, __shfl_xor(m, 4));
      m = fmaxf(m, __shfl_xor(m, 8));
      float s = 0.f;
#pragma unroll
      for (int ct = 0; ct < 4; ++ct) {
        float p = __expf(sv[ct][r] - m);
        sv[ct][r] = p;
        s += p;
      }
      s += __shfl_xor(s, 1);
      s += __shfl_xor(s, 2);
      s += __shfl_xor(s, 4);
      s += __shfl_xor(s, 8);
      rsum[r] = s;
    }
#pragma unroll
    for (int ct = 0; ct < 4; ++ct)
#pragma unroll
      for (int r = 0; r < 4; ++r) {
        int row = 16 * w + (lg << 2) + r;
        int col = 16 * ct + li;
        Q[row * 64 + (((col >> 3) ^ (row & 7)) << 3) + (col & 7)] = (bf16)sv[ct][r];
      }
    f32x4 accO[4] = {};
#pragma unroll
    for (int kk = 0; kk < 2; ++kk) {
      int row = 16 * w + li;
      bf16x8 ap = *((const bf16x8*)&Q[row * 64 + (((kk * 4 + lg) ^ (row & 7)) << 3)]);
#pragma unroll
      for (int ct = 0; ct < 4; ++ct) {
        int vr = 16 * ct + li;
        bf16x8 bv = *((const bf16x8*)&V[vr * 64 + (((kk * 4 + lg) ^ (vr & 7)) << 3)]);
        accO[ct] = MFMA(ap, bv, accO[ct]);
      }
    }
    bf16* ob = qkv + (((size_t)b * 8 + h) << 12);
    float rinv[4];
#pragma unroll
    for (int r = 0; r < 4; ++r) rinv[r] = 1.0f / rsum[r];
#pragma unroll
    for (int ct = 0; ct < 4; ++ct)
#pragma unroll
      for (int r = 0; r < 4; ++r)
        ob[(16 * w + (lg << 2) + r) * 64 + 16 * ct + li] = (bf16)(accO[ct][r] * rinv[r]);
  }
}

extern "C" void kernel_launch(void* const* d_in, const int* in_sizes, int n_in,
                              void* d_out, int out_size, void* d_ws, size_t ws_size,
                              hipStream_t stream) {
  (void)in_sizes; (void)n_in; (void)out_size; (void)ws_size;
  const float* x       = (const float*)d_in[0];
  const float* temb    = (const float*)d_in[1];
  const float* w_qkv   = (const float*)d_in[2];
  const float* b_qkv   = (const float*)d_in[3];
  const float* w_qkv_t = (const float*)d_in[4];
  const float* w_proj  = (const float*)d_in[5];
  const float* b_proj  = (const float*)d_in[6];
  const float* rpb     = (const float*)d_in[7];
  float* out = (float*)d_out;

  char* ws = (char*)d_ws;
  size_t off = 0;
  auto take = [&](size_t bytes) {
    void* p = ws + off;
    off += (bytes + 255) & ~(size_t)255;
    return p;
  };
  bf16* w1t  = (bf16*)take((size_t)1536 * 512 * 2);
  bf16* w3t  = (bf16*)take((size_t)1536 * 512 * 2);
  bf16* w2t  = (bf16*)take((size_t)512 * 512 * 2);
  float* tb  = (float*)take((size_t)2048 * 1536 * 4);
  bf16* qkv  = (bf16*)take(3 * SEC * 2);          // q/k [b][h][n][d], vT [b][h][d][n]
  bf16* xb   = (bf16*)take((size_t)131072 * 512 * 2);  // x cast to bf16

  transpose_cast<<<(512 * 1536 + 255) / 256, 256, 0, stream>>>(w_qkv, w1t, 512, 1536);
  transpose_cast<<<(512 * 1536 + 255) / 256, 256, 0, stream>>>(w_qkv_t, w3t, 512, 1536);
  transpose_cast<<<(512 * 512 + 255) / 256, 256, 0, stream>>>(w_proj, w2t, 512, 512);

  cast_bf16<<<(131072 * 512 / 8) / 256, 256, 0, stream>>>(x, xb);

  gemm_temb<<<dim3(2048 / 128, 1536 / 128), 256, 0, stream>>>(
      temb, w3t, b_qkv, tb, 2048, 1536, 512);

  mm128<1><<<12 * 1024, 256, 0, stream>>>(xb, w1t, tb, qkv);

  attn_win<<<2048, 256, 0, stream>>>(qkv, rpb);

  mm128<0><<<4 * 1024, 256, 0, stream>>>(qkv, w2t, b_proj, out);
}